// Round 1
// baseline (78.845 us; speedup 1.0000x reference)
//
#include <hip/hip_runtime.h>
#include <math.h>

// Problem constants (from reference): B=2048, P_ROWS=128, N=64, Q=8
#define NB    2048
#define PROWS 128
#define NDIM  64
#define QCNT  8

// One block per batch element. 256 threads = 4 waves.
// Memory-bound: streams A1 (32KB/batch) + P (128KB/batch) exactly once.
__global__ __launch_bounds__(256) void constraint_kernel(
    const float* __restrict__ v,    // (B, 64)
    const float* __restrict__ A1,   // (B, 128, 64)
    const float* __restrict__ b1,   // (B, 128)
    const float* __restrict__ z0,   // (B, 64)
    const float* __restrict__ P,    // (B, 8, 64, 64)
    const float* __restrict__ qv,   // (B, 8, 64)
    const float* __restrict__ rr,   // (B, 8)
    float* __restrict__ out)        // (B, 64)
{
    const int b   = blockIdx.x;
    const int tid = threadIdx.x;

    __shared__ __align__(16) float s_rho[NDIM];
    __shared__ __align__(16) float s_y0[NDIM];
    __shared__ float s_part[4][4];
    __shared__ float s_wmax[4];
    __shared__ float s_norm;
    __shared__ float s_klin;
    __shared__ float s_alpha;

    // ---------- Phase A: norm_v, rho = v/||v||, y0 = z0 ----------
    float vval = 0.f;
    if (tid < NDIM) {
        vval = v[b * NDIM + tid];
        s_y0[tid] = z0[b * NDIM + tid];
    }
    if (tid < 64) {  // wave 0 (all 64 lanes active)
        float s = vval * vval;
        #pragma unroll
        for (int m = 32; m >= 1; m >>= 1) s += __shfl_xor(s, m);
        if (tid == 0) s_norm = sqrtf(s);
    }
    __syncthreads();
    const float norm_v = s_norm;
    if (tid < NDIM) s_rho[tid] = vval / norm_v;
    __syncthreads();

    // ---------- Phase B: linear kappa = relu(max_rows (A1 rho) / (b1 - A1 z0)) ----------
    // 16 threads per row; each thread loads one float4 (cols sub*4..sub*4+3).
    const int sub = tid & 15;   // 0..15 within row group
    const int grp = tid >> 4;   // 0..15 row group id
    const float4 rho4 = *(const float4*)&s_rho[sub * 4];
    const float4 z04  = *(const float4*)&s_y0[sub * 4];

    float lmax = -INFINITY;
    const float* A1b = A1 + (size_t)b * PROWS * NDIM;
    #pragma unroll
    for (int p = 0; p < PROWS / 16; ++p) {
        const int row = p * 16 + grp;
        const float4 a = *(const float4*)&A1b[row * NDIM + sub * 4];
        float dv = a.x * rho4.x + a.y * rho4.y + a.z * rho4.z + a.w * rho4.w;
        float dz = a.x * z04.x  + a.y * z04.y  + a.z * z04.z  + a.w * z04.w;
        #pragma unroll
        for (int m = 8; m >= 1; m >>= 1) {
            dv += __shfl_xor(dv, m);
            dz += __shfl_xor(dz, m);
        }
        if (sub == 0) {
            const float denom = b1[b * PROWS + row] - dz;
            lmax = fmaxf(lmax, dv / denom);
        }
    }
    // block max of lmax
    #pragma unroll
    for (int m = 32; m >= 1; m >>= 1) lmax = fmaxf(lmax, __shfl_xor(lmax, m));
    if ((tid & 63) == 0) s_wmax[tid >> 6] = lmax;
    __syncthreads();
    if (tid == 0) {
        const float km = fmaxf(fmaxf(s_wmax[0], s_wmax[1]), fmaxf(s_wmax[2], s_wmax[3]));
        s_klin = fmaxf(km, 0.f);  // relu
    }

    // ---------- Phase C: quadratic kappas ----------
    // Thread owns row i = tid>>2, column subset s4: cols { k*16 + s4*4 .. +3 } for k=0..3.
    // Accumulate three bilinear forms directly (no Py0 / P rho vectors):
    //   rPr = rho^T P rho, gr = rho^T P y0 + q.rho, yPy = y0^T P y0, qy = q.y0
    const int i  = tid >> 2;
    const int s4 = tid & 3;
    const float rho_i = s_rho[i];
    const float y0_i  = s_y0[i];
    float4 rj[4], yj[4];
    #pragma unroll
    for (int k = 0; k < 4; ++k) {
        rj[k] = *(const float4*)&s_rho[k * 16 + s4 * 4];
        yj[k] = *(const float4*)&s_y0[k * 16 + s4 * 4];
    }

    float kqmax = -INFINITY;  // tracked by tid 0 only
    const float* Pb = P + (size_t)b * QCNT * NDIM * NDIM;
    for (int qq = 0; qq < QCNT; ++qq) {
        const float* Pq = Pb + qq * NDIM * NDIM + i * NDIM;
        float dr = 0.f, dy = 0.f;
        #pragma unroll
        for (int k = 0; k < 4; ++k) {
            const float4 p4 = *(const float4*)&Pq[k * 16 + s4 * 4];
            dr += p4.x * rj[k].x + p4.y * rj[k].y + p4.z * rj[k].z + p4.w * rj[k].w;
            dy += p4.x * yj[k].x + p4.y * yj[k].y + p4.z * yj[k].z + p4.w * yj[k].w;
        }
        float a0 = rho_i * dr;   // -> rPr
        float a1 = rho_i * dy;   // -> rho^T P y0 (part of gr)
        float a2 = y0_i  * dy;   // -> y0^T P y0
        float a3 = 0.f;          // -> q.y0
        if (s4 == 0) {
            const float qvi = qv[(size_t)b * QCNT * NDIM + qq * NDIM + i];
            a1 += qvi * rho_i;   // + q.rho -> completes gr
            a3  = qvi * y0_i;
        }
        #pragma unroll
        for (int m = 32; m >= 1; m >>= 1) {
            a0 += __shfl_xor(a0, m);
            a1 += __shfl_xor(a1, m);
            a2 += __shfl_xor(a2, m);
            a3 += __shfl_xor(a3, m);
        }
        if ((tid & 63) == 0) {
            const int w = tid >> 6;
            s_part[w][0] = a0; s_part[w][1] = a1;
            s_part[w][2] = a2; s_part[w][3] = a3;
        }
        __syncthreads();
        if (tid == 0) {
            const float rPr = s_part[0][0] + s_part[1][0] + s_part[2][0] + s_part[3][0];
            const float gr  = s_part[0][1] + s_part[1][1] + s_part[2][1] + s_part[3][1];
            const float yPy = s_part[0][2] + s_part[1][2] + s_part[2][2] + s_part[3][2];
            const float qy  = s_part[0][3] + s_part[1][3] + s_part[2][3] + s_part[3][3];
            const float c0    = 0.5f * yPy + qy + rr[b * QCNT + qq];
            const float sigma = 2.f * c0;
            const float quad  = (gr * gr - 2.f * c0 * rPr) / (sigma * sigma);
            const float kq    = -gr / sigma + sqrtf(quad);
            kqmax = fmaxf(kqmax, kq);
        }
        __syncthreads();  // s_part reused next iteration
    }

    // ---------- Epilogue ----------
    if (tid == 0) {
        const float kappa = fmaxf(s_klin, kqmax);
        const float alpha = fminf(1.f / kappa, norm_v);  // 1/0 = inf -> picks norm_v
        s_alpha = alpha;
    }
    __syncthreads();
    if (tid < NDIM) {
        out[b * NDIM + tid] = s_y0[tid] + s_alpha * s_rho[tid];
    }
}

extern "C" void kernel_launch(void* const* d_in, const int* in_sizes, int n_in,
                              void* d_out, int out_size, void* d_ws, size_t ws_size,
                              hipStream_t stream) {
    const float* v  = (const float*)d_in[0];
    const float* A1 = (const float*)d_in[1];
    const float* b1 = (const float*)d_in[2];
    const float* z0 = (const float*)d_in[3];
    const float* P  = (const float*)d_in[4];
    const float* qv = (const float*)d_in[5];
    const float* rr = (const float*)d_in[6];
    float* out = (float*)d_out;

    constraint_kernel<<<NB, 256, 0, stream>>>(v, A1, b1, z0, P, qv, rr, out);
}